// Round 4
// baseline (161.534 us; speedup 1.0000x reference)
//
#include <hip/hip_runtime.h>
#include <utility>

// EquivariantProductBasisBlock (MACE-style) for gfx950 — round 4.
// Round-3 learned: 512 blocks x 256 thr = 2 blocks/CU = 8 waves/CU -> occupancy
// 19%, VALUBusy 23%; latency-bound, NOT L2-bound (4x weight-traffic cut was
// neutral). Round 4: same algorithm, 512-thread blocks (8 waves), 512 blocks,
// __launch_bounds__(512,4) caps VGPR at 128 -> 2 blocks/CU = 16 waves/CU (50%).

#define NN 4096
#define NC 128
#define TN 8

// ---------------------------- static_for ---------------------------------------
template<typename F, int... Is>
__device__ __forceinline__ void sfor_impl(F&& f, std::integer_sequence<int, Is...>) {
  (f(std::integral_constant<int, Is>{}), ...);
}
template<int N, typename F>
__device__ __forceinline__ void sfor(F&& f) {
  sfor_impl((F&&)f, std::make_integer_sequence<int, N>{});
}

// ---------------------------- CG metadata (constexpr) --------------------------
constexpr int T_L1c[19]  = {0,0,0,1,1,1,1,1,1,1,2,2,2,2,2,2,2,2,3};
constexpr int T_L2c[19]  = {0,1,2,0,1,1,1,2,2,2,0,1,1,1,2,2,2,2,2};
constexpr int T_L3c[19]  = {0,1,2,1,0,1,2,1,2,3,2,1,2,3,0,1,2,3,1};
constexpr int T_OFFc[19] = {0,1,10,35,44,53,80,125,170,245,350,375,420,495,600,625,700,825,1000};
constexpr int AOFFc[3]   = {0,1,4};

constexpr int P2_L1c[9]  = {0,0,1,1,1,1,2,2,2};
constexpr int P2_L2c[9]  = {0,1,0,1,1,2,1,2,2};
constexpr int P2_LOc[9]  = {0,1,1,0,1,1,1,0,1};
constexpr int P2_TBLc[9] = {0,1,3,4,5,7,11,14,15};

constexpr int K_L1c[18]  = {0,0,0,1,1,1,1,1,1,1,2,2,2,2,2,2,2,2};
constexpr int K_L2c[18]  = {0,1,2,0,1,1,1,2,2,2,0,1,1,1,2,2,2,2};
constexpr int K_L12c[18] = {0,1,2,1,0,1,2,1,2,3,2,1,2,3,0,1,2,3};

constexpr int P3_STARTc[19] = {0,2,6,9,13,15,19,22,26,29,30,33,37,40,41,43,47,50,51};
constexpr int P3_L3c[51] = {
  0,1,  0,1,1,2,  1,2,2,  0,1,1,2,  0,1,  0,1,1,2,  1,2,2,  0,1,1,2,  1,2,2,
  2,  1,2,2,  0,1,1,2,  1,2,2,  2,  0,1,  0,1,1,2,  1,2,2,  2 };
constexpr int P3_LOc[51] = {
  0,1,  1,0,1,1,  1,0,1,  1,0,1,1,  0,1,  1,0,1,1,  1,0,1,  1,0,1,1,  1,0,1,
  1,  1,0,1,  1,0,1,1,  1,0,1,  1,  0,1,  1,0,1,1,  1,0,1,  1 };
constexpr int P3_TBLc[51] = {
  0,1,  3,4,5,7,  11,14,15,  3,4,5,7,  0,1,  3,4,5,7,  11,14,15,  3,4,5,7,
  11,14,15,  18,  11,14,15,  3,4,5,7,  11,14,15,  18,  0,1,  3,4,5,7,
  11,14,15,  18 };

// ---------------------------- constexpr CG computation -------------------------
constexpr double cfact(int n) { double r = 1.0; for (int i = 2; i <= n; ++i) r *= i; return r; }
constexpr double csqrt(double x) {
  if (x <= 0.0) return 0.0;
  double r = x > 1.0 ? x : 1.0;
  for (int i = 0; i < 64; ++i) r = 0.5 * (r + x / r);
  return r;
}
constexpr double su2cg(int j1, int m1, int j2, int m2, int j3, int m3) {
  if (m3 != m1 + m2) return 0.0;
  int vmin = -j1 + j2 + m3; if (-j1 + m1 > vmin) vmin = -j1 + m1; if (vmin < 0) vmin = 0;
  int vmax = j2 + j3 + m1; if (j3 - j1 + j2 < vmax) vmax = j3 - j1 + j2; if (j3 + m3 < vmax) vmax = j3 + m3;
  double C = csqrt((2.0 * j3 + 1.0)
                   * cfact(j3 + j1 - j2) * cfact(j3 - j1 + j2) * cfact(j1 + j2 - j3)
                   * cfact(j3 + m3) * cfact(j3 - m3)
                   / (cfact(j1 + j2 + j3 + 1) * cfact(j1 - m1) * cfact(j1 + m1)
                      * cfact(j2 - m2) * cfact(j2 + m2)));
  double S = 0.0;
  for (int v = vmin; v <= vmax; ++v) {
    double sgn = ((v + j2 + m2) & 1) ? -1.0 : 1.0;
    S += sgn * cfact(j2 + j3 + m1 - v) * cfact(j1 - m1 + v)
         / (cfact(v) * cfact(j3 - j1 + j2 - v) * cfact(j3 + m3 - v) * cfact(v + j1 - j2 - m3));
  }
  return C * S;
}

struct Cx { double re, im; };
constexpr Cx cxmul(Cx a, Cx b) { return Cx{a.re * b.re - a.im * b.im, a.re * b.im + a.im * b.re}; }
struct Row { int cnt; int col[2]; Cx v[2]; };

constexpr Row c2r_row(int l, int r) {
  Row out{0, {0, 0}, {{0, 0}, {0, 0}}};
  constexpr double is2 = 0.70710678118654752440;
  const int m = r - l;
  if (m < 0) {
    out.cnt = 2;
    out.col[0] = l - m; out.v[0] = Cx{is2, 0.0};
    out.col[1] = l + m; out.v[1] = Cx{0.0, -is2};
  } else if (m == 0) {
    out.cnt = 1; out.col[0] = l; out.v[0] = Cx{1.0, 0.0};
  } else {
    const double sgn = (m & 1) ? -1.0 : 1.0;
    out.cnt = 2;
    out.col[0] = l + m; out.v[0] = Cx{sgn * is2, 0.0};
    out.col[1] = l - m; out.v[1] = Cx{0.0, sgn * is2};
  }
  const int ph = l & 3;
  for (int a = 0; a < out.cnt; ++a) {
    Cx v = out.v[a];
    out.v[a] = (ph == 0) ? v
             : (ph == 1) ? Cx{v.im, -v.re}
             : (ph == 2) ? Cx{-v.re, -v.im}
                         : Cx{-v.im, v.re};
  }
  return out;
}

struct CGAll { float v[1105]; };
constexpr CGAll make_cg() {
  CGAll R{};
  for (int t = 0; t < 19; ++t) {
    const int l1 = T_L1c[t], l2 = T_L2c[t], l3 = T_L3c[t], off = T_OFFc[t];
    const int d1 = 2 * l1 + 1, d2 = 2 * l2 + 1, d3 = 2 * l3 + 1;
    double tmp[175] = {};
    for (int i = 0; i < d1; ++i) {
      const int m1 = i - l1;
      const Row r1 = c2r_row(l1, i);
      for (int k = 0; k < d2; ++k) {
        const int m2 = k - l2, m3 = m1 + m2;
        if (m3 < -l3 || m3 > l3) continue;
        const double cc = su2cg(l1, m1, l2, m2, l3, m3);
        if (cc == 0.0) continue;
        const Row r2 = c2r_row(l2, k);
        const Row r3 = c2r_row(l3, m3 + l3);
        for (int a = 0; a < r1.cnt; ++a)
          for (int b = 0; b < r2.cnt; ++b) {
            const Cx q12 = cxmul(r1.v[a], r2.v[b]);
            for (int cdx = 0; cdx < r3.cnt; ++cdx) {
              const double re = q12.re * r3.v[cdx].re + q12.im * r3.v[cdx].im;
              tmp[(r1.col[a] * d2 + r2.col[b]) * d3 + r3.col[cdx]] += re * cc;
            }
          }
      }
    }
    const int sz = d1 * d2 * d3;
    for (int e = 0; e < sz; ++e) R.v[off + e] = (float)tmp[e];
  }
  return R;
}
constexpr CGAll CG_ALL = make_cg();

// ------------------------- basis for one (node,channel) pair -------------------
__device__ __forceinline__ void basis_pair(
    const float* __restrict__ Ap,      // 9 floats (LDS)
    const float* __restrict__ w1p,     // stride NC between paths
    const float* __restrict__ w2p,
    const float* __restrict__ w3p,
    float B[4])
{
  float A[9];
  #pragma unroll
  for (int i = 0; i < 9; ++i) A[i] = Ap[i];

  B[0] = B[1] = B[2] = B[3] = 0.f;

  // ---- order 1
  {
    const float w10 = w1p[0];
    const float w11 = w1p[NC];
    B[0] = fmaf(w10, A[0], B[0]);
    B[1] = fmaf(w11, A[1], B[1]);
    B[2] = fmaf(w11, A[2], B[2]);
    B[3] = fmaf(w11, A[3], B[3]);
  }

  // ---- order 2
  sfor<9>([&](auto P) {
    constexpr int p  = P.value;
    constexpr int l1 = P2_L1c[p], l2 = P2_L2c[p], lo = P2_LOc[p];
    constexpr int d1 = 2 * l1 + 1, d2 = 2 * l2 + 1, dl = 2 * lo + 1;
    constexpr int off = T_OFFc[P2_TBLc[p]];
    const float w = w2p[p * NC];
    sfor<dl>([&](auto Kk) {
      constexpr int k = Kk.value;
      float v = 0.f;
      sfor<d1>([&](auto I) {
        sfor<d2>([&](auto J) {
          constexpr float cgc = CG_ALL.v[off + (I.value * d2 + J.value) * dl + k];
          if constexpr (cgc != 0.0f) {
            constexpr int ia = AOFFc[l1] + I.value, ja = AOFFc[l2] + J.value;
            constexpr int x = ia < ja ? ia : ja, y = ia < ja ? ja : ia;
            v = fmaf(cgc, A[x] * A[y], v);
          }
        });
      });
      B[lo + k] = fmaf(w, v, B[lo + k]);
    });
  });

  // ---- order 3
  sfor<18>([&](auto T) {
    constexpr int t   = T.value;
    constexpr int l1  = K_L1c[t], l2 = K_L2c[t], l12 = K_L12c[t];
    constexpr int d1  = 2 * l1 + 1, d2 = 2 * l2 + 1, d12 = 2 * l12 + 1;
    constexpr int off = T_OFFc[t];
    float tt[d12];
    sfor<d12>([&](auto Kk) {
      constexpr int k = Kk.value;
      float v = 0.f;
      sfor<d1>([&](auto I) {
        sfor<d2>([&](auto J) {
          constexpr float cgc = CG_ALL.v[off + (I.value * d2 + J.value) * d12 + k];
          if constexpr (cgc != 0.0f) {
            constexpr int ia = AOFFc[l1] + I.value, ja = AOFFc[l2] + J.value;
            constexpr int x = ia < ja ? ia : ja, y = ia < ja ? ja : ia;
            v = fmaf(cgc, A[x] * A[y], v);
          }
        });
      });
      tt[k] = v;
    });
    constexpr int pcnt = P3_STARTc[t + 1] - P3_STARTc[t];
    sfor<pcnt>([&](auto PP) {
      constexpr int p  = P3_STARTc[t] + PP.value;
      constexpr int l3 = P3_L3c[p], lo = P3_LOc[p];
      constexpr int d3 = 2 * l3 + 1, dl = 2 * lo + 1;
      constexpr int off2 = T_OFFc[P3_TBLc[p]];
      const float w = w3p[p * NC];
      sfor<dl>([&](auto M) {
        float v = 0.f;
        sfor<d12>([&](auto Kk) {
          sfor<d3>([&](auto J) {
            constexpr float cgc = CG_ALL.v[off2 + (Kk.value * d3 + J.value) * dl + M.value];
            if constexpr (cgc != 0.0f)
              v = fmaf(cgc, tt[Kk.value] * A[AOFFc[l3] + J.value], v);
          });
        });
        B[lo + M.value] = fmaf(w, v, B[lo + M.value]);
      });
    });
  });
}

// ------------------------------- main kernel -----------------------------------
__global__ __launch_bounds__(512, 4) void epb_main(
    const float* __restrict__ nf,      // [N, C, 9]
    const float* __restrict__ w1,      // [E, 2, C]
    const float* __restrict__ w2,      // [E, 9, C]
    const float* __restrict__ w3,      // [E, 51, C]
    const float* __restrict__ lw0,     // [C, F=128]
    const float* __restrict__ lw1,     // [C, F=128]
    const int*   __restrict__ species, // [N]
    float* __restrict__ out)           // [N, F, 4]
{
  __shared__ float  Anf[TN * NC * 9];  // 36 KB
  __shared__ float4 Bsh[TN * NC];      // 16 KB  [node][channel]
  const int t  = threadIdx.x;
  const int nb = blockIdx.x * TN;

  // ---- stage node_feats tile (coalesced float4): 2304 float4 over 512 threads
  {
    const float4* src = reinterpret_cast<const float4*>(nf + (size_t)nb * (NC * 9));
    float4* dst = reinterpret_cast<float4*>(Anf);
    #pragma unroll
    for (int i = 0; i < 4; ++i) dst[t + 512 * i] = src[t + 512 * i];
    if (t < 256) dst[t + 2048] = src[t + 2048];
  }
  __syncthreads();

  // ---- basis: 2 (node,channel) pairs per thread
  {
    const int c = t & 127, h = t >> 7;          // h in 0..3
    #pragma unroll 1
    for (int q = 0; q < 2; ++q) {
      const int nl = h + 4 * q;
      const int s  = species[nb + nl];
      const float* w1p = w1 + (size_t)s * 2  * NC + c;
      const float* w2p = w2 + (size_t)s * 9  * NC + c;
      const float* w3p = w3 + (size_t)s * 51 * NC + c;
      float B[4];
      basis_pair(Anf + nl * (NC * 9) + c * 9, w1p, w2p, w3p, B);
      Bsh[nl * NC + c] = make_float4(B[0], B[1], B[2], B[3]);
    }
  }
  __syncthreads();

  // ---- linear: 1 feature x 2 nodes per thread (weights reused across 2 nodes)
  const int fl = t & 127, g = t >> 7;   // g in 0..3: nodes g and g+4
  const float* pa = lw0 + fl;
  const float* pb = lw1 + fl;
  const float4* b0p = &Bsh[g * NC];
  const float4* b1p = &Bsh[(g + 4) * NC];

  float a00 = 0.f, a01 = 0.f, a02 = 0.f, a03 = 0.f;   // node g
  float a10 = 0.f, a11 = 0.f, a12 = 0.f, a13 = 0.f;   // node g+4

  #pragma unroll 8
  for (int ch = 0; ch < NC; ++ch) {
    const float wa = pa[ch * NC];      // coalesced across fl
    const float wb = pb[ch * NC];
    const float4 b0 = b0p[ch];         // wave-uniform -> LDS broadcast
    const float4 b1 = b1p[ch];
    a00 = fmaf(b0.x, wa, a00); a01 = fmaf(b0.y, wb, a01);
    a02 = fmaf(b0.z, wb, a02); a03 = fmaf(b0.w, wb, a03);
    a10 = fmaf(b1.x, wa, a10); a11 = fmaf(b1.y, wb, a11);
    a12 = fmaf(b1.z, wb, a12); a13 = fmaf(b1.w, wb, a13);
  }

  const float s4 = 0.08838834764831845f;  // 1/sqrt(128)
  float4* out4 = reinterpret_cast<float4*>(out);
  out4[(size_t)(nb + g) * NC + fl]     = make_float4(a00*s4, a01*s4, a02*s4, a03*s4);
  out4[(size_t)(nb + g + 4) * NC + fl] = make_float4(a10*s4, a11*s4, a12*s4, a13*s4);
}

// ------------------------------- launcher --------------------------------------
extern "C" void kernel_launch(void* const* d_in, const int* in_sizes, int n_in,
                              void* d_out, int out_size, void* d_ws, size_t ws_size,
                              hipStream_t stream) {
  const float* nf  = (const float*)d_in[0];
  const float* w1  = (const float*)d_in[1];
  const float* w2  = (const float*)d_in[2];
  const float* w3  = (const float*)d_in[3];
  const float* lw0 = (const float*)d_in[4];
  const float* lw1 = (const float*)d_in[5];
  const int*   spc = (const int*)  d_in[6];
  float* out = (float*)d_out;
  (void)d_ws; (void)ws_size; (void)in_sizes; (void)n_in; (void)out_size;

  hipLaunchKernelGGL(epb_main, dim3(NN / TN), dim3(512), 0, stream,
                     nf, w1, w2, w3, lw0, lw1, spc, out);
}

// Round 5
// 143.410 us; speedup vs baseline: 1.1264x; 1.1264x over previous
//
#include <hip/hip_runtime.h>
#include <utility>

// EquivariantProductBasisBlock (MACE-style) for gfx950 — round 5.
// R4 lesson: launch_bounds(512,4) -> 64 VGPR -> spill storm (WRITE_SIZE 219MB).
// R2/R3 plateau diagnosis: 62 scalar stride-512B weight loads interleaved with
// FMAs -> load-use stalls, VALU duty ~30%. R5: pre-pack weights to one 64-float
// contiguous record per (species,channel) in d_ws; basis issues 16 dwordx4
// up-front -> one waitcnt then straight-line FMA. TN=4, 256-thr blocks, 1024
// blocks (4/CU), launch_bounds(256,3) caps VGPR at 170 (no spill).

#define NN 4096
#define NC 128
#define NE 10
#define TN 4
#define WREC 64   // packed weight record: [0..1]=w1, [2..10]=w2, [11..61]=w3, pad

// ---------------------------- static_for ---------------------------------------
template<typename F, int... Is>
__device__ __forceinline__ void sfor_impl(F&& f, std::integer_sequence<int, Is...>) {
  (f(std::integral_constant<int, Is>{}), ...);
}
template<int N, typename F>
__device__ __forceinline__ void sfor(F&& f) {
  sfor_impl((F&&)f, std::make_integer_sequence<int, N>{});
}

// ---------------------------- CG metadata (constexpr) --------------------------
constexpr int T_L1c[19]  = {0,0,0,1,1,1,1,1,1,1,2,2,2,2,2,2,2,2,3};
constexpr int T_L2c[19]  = {0,1,2,0,1,1,1,2,2,2,0,1,1,1,2,2,2,2,2};
constexpr int T_L3c[19]  = {0,1,2,1,0,1,2,1,2,3,2,1,2,3,0,1,2,3,1};
constexpr int T_OFFc[19] = {0,1,10,35,44,53,80,125,170,245,350,375,420,495,600,625,700,825,1000};
constexpr int AOFFc[3]   = {0,1,4};

constexpr int P2_L1c[9]  = {0,0,1,1,1,1,2,2,2};
constexpr int P2_L2c[9]  = {0,1,0,1,1,2,1,2,2};
constexpr int P2_LOc[9]  = {0,1,1,0,1,1,1,0,1};
constexpr int P2_TBLc[9] = {0,1,3,4,5,7,11,14,15};

constexpr int K_L1c[18]  = {0,0,0,1,1,1,1,1,1,1,2,2,2,2,2,2,2,2};
constexpr int K_L2c[18]  = {0,1,2,0,1,1,1,2,2,2,0,1,1,1,2,2,2,2};
constexpr int K_L12c[18] = {0,1,2,1,0,1,2,1,2,3,2,1,2,3,0,1,2,3};

constexpr int P3_STARTc[19] = {0,2,6,9,13,15,19,22,26,29,30,33,37,40,41,43,47,50,51};
constexpr int P3_L3c[51] = {
  0,1,  0,1,1,2,  1,2,2,  0,1,1,2,  0,1,  0,1,1,2,  1,2,2,  0,1,1,2,  1,2,2,
  2,  1,2,2,  0,1,1,2,  1,2,2,  2,  0,1,  0,1,1,2,  1,2,2,  2 };
constexpr int P3_LOc[51] = {
  0,1,  1,0,1,1,  1,0,1,  1,0,1,1,  0,1,  1,0,1,1,  1,0,1,  1,0,1,1,  1,0,1,
  1,  1,0,1,  1,0,1,1,  1,0,1,  1,  0,1,  1,0,1,1,  1,0,1,  1 };
constexpr int P3_TBLc[51] = {
  0,1,  3,4,5,7,  11,14,15,  3,4,5,7,  0,1,  3,4,5,7,  11,14,15,  3,4,5,7,
  11,14,15,  18,  11,14,15,  3,4,5,7,  11,14,15,  18,  0,1,  3,4,5,7,
  11,14,15,  18 };

// ---------------------------- constexpr CG computation -------------------------
constexpr double cfact(int n) { double r = 1.0; for (int i = 2; i <= n; ++i) r *= i; return r; }
constexpr double csqrt(double x) {
  if (x <= 0.0) return 0.0;
  double r = x > 1.0 ? x : 1.0;
  for (int i = 0; i < 64; ++i) r = 0.5 * (r + x / r);
  return r;
}
constexpr double su2cg(int j1, int m1, int j2, int m2, int j3, int m3) {
  if (m3 != m1 + m2) return 0.0;
  int vmin = -j1 + j2 + m3; if (-j1 + m1 > vmin) vmin = -j1 + m1; if (vmin < 0) vmin = 0;
  int vmax = j2 + j3 + m1; if (j3 - j1 + j2 < vmax) vmax = j3 - j1 + j2; if (j3 + m3 < vmax) vmax = j3 + m3;
  double C = csqrt((2.0 * j3 + 1.0)
                   * cfact(j3 + j1 - j2) * cfact(j3 - j1 + j2) * cfact(j1 + j2 - j3)
                   * cfact(j3 + m3) * cfact(j3 - m3)
                   / (cfact(j1 + j2 + j3 + 1) * cfact(j1 - m1) * cfact(j1 + m1)
                      * cfact(j2 - m2) * cfact(j2 + m2)));
  double S = 0.0;
  for (int v = vmin; v <= vmax; ++v) {
    double sgn = ((v + j2 + m2) & 1) ? -1.0 : 1.0;
    S += sgn * cfact(j2 + j3 + m1 - v) * cfact(j1 - m1 + v)
         / (cfact(v) * cfact(j3 - j1 + j2 - v) * cfact(j3 + m3 - v) * cfact(v + j1 - j2 - m3));
  }
  return C * S;
}

struct Cx { double re, im; };
constexpr Cx cxmul(Cx a, Cx b) { return Cx{a.re * b.re - a.im * b.im, a.re * b.im + a.im * b.re}; }
struct Row { int cnt; int col[2]; Cx v[2]; };

constexpr Row c2r_row(int l, int r) {
  Row out{0, {0, 0}, {{0, 0}, {0, 0}}};
  constexpr double is2 = 0.70710678118654752440;
  const int m = r - l;
  if (m < 0) {
    out.cnt = 2;
    out.col[0] = l - m; out.v[0] = Cx{is2, 0.0};
    out.col[1] = l + m; out.v[1] = Cx{0.0, -is2};
  } else if (m == 0) {
    out.cnt = 1; out.col[0] = l; out.v[0] = Cx{1.0, 0.0};
  } else {
    const double sgn = (m & 1) ? -1.0 : 1.0;
    out.cnt = 2;
    out.col[0] = l + m; out.v[0] = Cx{sgn * is2, 0.0};
    out.col[1] = l - m; out.v[1] = Cx{0.0, sgn * is2};
  }
  const int ph = l & 3;
  for (int a = 0; a < out.cnt; ++a) {
    Cx v = out.v[a];
    out.v[a] = (ph == 0) ? v
             : (ph == 1) ? Cx{v.im, -v.re}
             : (ph == 2) ? Cx{-v.re, -v.im}
                         : Cx{-v.im, v.re};
  }
  return out;
}

struct CGAll { float v[1105]; };
constexpr CGAll make_cg() {
  CGAll R{};
  for (int t = 0; t < 19; ++t) {
    const int l1 = T_L1c[t], l2 = T_L2c[t], l3 = T_L3c[t], off = T_OFFc[t];
    const int d1 = 2 * l1 + 1, d2 = 2 * l2 + 1, d3 = 2 * l3 + 1;
    double tmp[175] = {};
    for (int i = 0; i < d1; ++i) {
      const int m1 = i - l1;
      const Row r1 = c2r_row(l1, i);
      for (int k = 0; k < d2; ++k) {
        const int m2 = k - l2, m3 = m1 + m2;
        if (m3 < -l3 || m3 > l3) continue;
        const double cc = su2cg(l1, m1, l2, m2, l3, m3);
        if (cc == 0.0) continue;
        const Row r2 = c2r_row(l2, k);
        const Row r3 = c2r_row(l3, m3 + l3);
        for (int a = 0; a < r1.cnt; ++a)
          for (int b = 0; b < r2.cnt; ++b) {
            const Cx q12 = cxmul(r1.v[a], r2.v[b]);
            for (int cdx = 0; cdx < r3.cnt; ++cdx) {
              const double re = q12.re * r3.v[cdx].re + q12.im * r3.v[cdx].im;
              tmp[(r1.col[a] * d2 + r2.col[b]) * d3 + r3.col[cdx]] += re * cc;
            }
          }
      }
    }
    const int sz = d1 * d2 * d3;
    for (int e = 0; e < sz; ++e) R.v[off + e] = (float)tmp[e];
  }
  return R;
}
constexpr CGAll CG_ALL = make_cg();

// ------------------- weight pack: [E][C][64] contiguous records ----------------
// record idx: 0..1 = w1 paths, 2..10 = w2 paths, 11..61 = w3 paths, 62..63 = 0
__global__ __launch_bounds__(256) void wt_pack(
    const float* __restrict__ w1,   // [E, 2, C]
    const float* __restrict__ w2,   // [E, 9, C]
    const float* __restrict__ w3,   // [E, 51, C]
    float4* __restrict__ wpack)     // [E*C*16] float4
{
  const int tid = blockIdx.x * 256 + threadIdx.x;   // E*C*16 = 20480
  if (tid >= NE * NC * 16) return;
  const int e  = tid / (NC * 16);
  const int r  = tid % (NC * 16);
  const int c  = r / 16;
  const int i4 = r % 16;
  float v[4];
  #pragma unroll
  for (int j = 0; j < 4; ++j) {
    const int p = i4 * 4 + j;
    float x = 0.f;
    if (p < 2)        x = w1[((size_t)e * 2  + p)       * NC + c];
    else if (p < 11)  x = w2[((size_t)e * 9  + (p - 2)) * NC + c];
    else if (p < 62)  x = w3[((size_t)e * 51 + (p - 11))* NC + c];
    v[j] = x;
  }
  wpack[tid] = make_float4(v[0], v[1], v[2], v[3]);  // consecutive lanes -> coalesced
}

// ------------------- basis for one (node,channel) pair -------------------------
// wr[64] lives in VGPRs: loaded up-front as 16 dwordx4 by the caller.
__device__ __forceinline__ void basis_pair(
    const float* __restrict__ Ap,      // 9 floats (LDS)
    const float wr[WREC],
    float B[4])
{
  float A[9];
  #pragma unroll
  for (int i = 0; i < 9; ++i) A[i] = Ap[i];

  B[0] = B[1] = B[2] = B[3] = 0.f;

  // ---- order 1
  B[0] = fmaf(wr[0], A[0], B[0]);
  B[1] = fmaf(wr[1], A[1], B[1]);
  B[2] = fmaf(wr[1], A[2], B[2]);
  B[3] = fmaf(wr[1], A[3], B[3]);

  // ---- order 2
  sfor<9>([&](auto P) {
    constexpr int p  = P.value;
    constexpr int l1 = P2_L1c[p], l2 = P2_L2c[p], lo = P2_LOc[p];
    constexpr int d1 = 2 * l1 + 1, d2 = 2 * l2 + 1, dl = 2 * lo + 1;
    constexpr int off = T_OFFc[P2_TBLc[p]];
    const float w = wr[2 + p];
    sfor<dl>([&](auto Kk) {
      constexpr int k = Kk.value;
      float v = 0.f;
      sfor<d1>([&](auto I) {
        sfor<d2>([&](auto J) {
          constexpr float cgc = CG_ALL.v[off + (I.value * d2 + J.value) * dl + k];
          if constexpr (cgc != 0.0f) {
            constexpr int ia = AOFFc[l1] + I.value, ja = AOFFc[l2] + J.value;
            constexpr int x = ia < ja ? ia : ja, y = ia < ja ? ja : ia;
            v = fmaf(cgc, A[x] * A[y], v);
          }
        });
      });
      B[lo + k] = fmaf(w, v, B[lo + k]);
    });
  });

  // ---- order 3
  sfor<18>([&](auto T) {
    constexpr int t   = T.value;
    constexpr int l1  = K_L1c[t], l2 = K_L2c[t], l12 = K_L12c[t];
    constexpr int d1  = 2 * l1 + 1, d2 = 2 * l2 + 1, d12 = 2 * l12 + 1;
    constexpr int off = T_OFFc[t];
    float tt[d12];
    sfor<d12>([&](auto Kk) {
      constexpr int k = Kk.value;
      float v = 0.f;
      sfor<d1>([&](auto I) {
        sfor<d2>([&](auto J) {
          constexpr float cgc = CG_ALL.v[off + (I.value * d2 + J.value) * d12 + k];
          if constexpr (cgc != 0.0f) {
            constexpr int ia = AOFFc[l1] + I.value, ja = AOFFc[l2] + J.value;
            constexpr int x = ia < ja ? ia : ja, y = ia < ja ? ja : ia;
            v = fmaf(cgc, A[x] * A[y], v);
          }
        });
      });
      tt[k] = v;
    });
    constexpr int pcnt = P3_STARTc[t + 1] - P3_STARTc[t];
    sfor<pcnt>([&](auto PP) {
      constexpr int p  = P3_STARTc[t] + PP.value;
      constexpr int l3 = P3_L3c[p], lo = P3_LOc[p];
      constexpr int d3 = 2 * l3 + 1, dl = 2 * lo + 1;
      constexpr int off2 = T_OFFc[P3_TBLc[p]];
      const float w = wr[11 + p];
      sfor<dl>([&](auto M) {
        float v = 0.f;
        sfor<d12>([&](auto Kk) {
          sfor<d3>([&](auto J) {
            constexpr float cgc = CG_ALL.v[off2 + (Kk.value * d3 + J.value) * dl + M.value];
            if constexpr (cgc != 0.0f)
              v = fmaf(cgc, tt[Kk.value] * A[AOFFc[l3] + J.value], v);
          });
        });
        B[lo + M.value] = fmaf(w, v, B[lo + M.value]);
      });
    });
  });
}

// ------------------------------- main kernel -----------------------------------
__global__ __launch_bounds__(256, 3) void epb_main(
    const float* __restrict__ nf,      // [N, C, 9]
    const float4* __restrict__ wpack,  // [E*C*16] packed weights
    const float* __restrict__ lw0,     // [C, F=128]
    const float* __restrict__ lw1,     // [C, F=128]
    const int*   __restrict__ species, // [N]
    float* __restrict__ out)           // [N, F, 4]
{
  __shared__ float  Anf[TN * NC * 9];  // 18 KB
  __shared__ float4 Bsh[TN * NC];      //  8 KB  [node][channel]
  const int t  = threadIdx.x;
  const int nb = blockIdx.x * TN;

  // ---- stage node_feats tile (coalesced float4): 1152 float4 over 256 threads
  {
    const float4* src = reinterpret_cast<const float4*>(nf + (size_t)nb * (NC * 9));
    float4* dst = reinterpret_cast<float4*>(Anf);
    #pragma unroll
    for (int i = 0; i < 4; ++i) dst[t + 256 * i] = src[t + 256 * i];
    if (t < 128) dst[t + 1024] = src[t + 1024];
  }
  __syncthreads();

  // ---- basis: 2 (node,channel) pairs per thread, weights prefetched as dwordx4
  {
    const int c = t & 127, h = t >> 7;          // h in 0..1
    #pragma unroll 1
    for (int q = 0; q < 2; ++q) {
      const int nl = h + 2 * q;                 // node-local 0..3
      const int s  = species[nb + nl];
      float wr[WREC];
      {
        float4* wrv = reinterpret_cast<float4*>(wr);
        const float4* wp4 = wpack + ((size_t)s * NC + c) * 16;
        #pragma unroll
        for (int i = 0; i < 16; ++i) wrv[i] = wp4[i];  // 16 independent dwordx4
      }
      float B[4];
      basis_pair(Anf + nl * (NC * 9) + c * 9, wr, B);
      Bsh[nl * NC + c] = make_float4(B[0], B[1], B[2], B[3]);
    }
  }
  __syncthreads();

  // ---- linear: 1 feature x 2 nodes per thread (weights reused across 2 nodes)
  const int fl = t & 127, g = t >> 7;   // g in 0..1: nodes g and g+2
  const float* pa = lw0 + fl;
  const float* pb = lw1 + fl;
  const float4* b0p = &Bsh[g * NC];
  const float4* b1p = &Bsh[(g + 2) * NC];

  float a00 = 0.f, a01 = 0.f, a02 = 0.f, a03 = 0.f;   // node g
  float a10 = 0.f, a11 = 0.f, a12 = 0.f, a13 = 0.f;   // node g+2

  #pragma unroll 8
  for (int ch = 0; ch < NC; ++ch) {
    const float wa = pa[ch * NC];      // coalesced across fl
    const float wb = pb[ch * NC];
    const float4 b0 = b0p[ch];         // wave-uniform -> LDS broadcast
    const float4 b1 = b1p[ch];
    a00 = fmaf(b0.x, wa, a00); a01 = fmaf(b0.y, wb, a01);
    a02 = fmaf(b0.z, wb, a02); a03 = fmaf(b0.w, wb, a03);
    a10 = fmaf(b1.x, wa, a10); a11 = fmaf(b1.y, wb, a11);
    a12 = fmaf(b1.z, wb, a12); a13 = fmaf(b1.w, wb, a13);
  }

  const float s4 = 0.08838834764831845f;  // 1/sqrt(128)
  float4* out4 = reinterpret_cast<float4*>(out);
  out4[(size_t)(nb + g) * NC + fl]     = make_float4(a00*s4, a01*s4, a02*s4, a03*s4);
  out4[(size_t)(nb + g + 2) * NC + fl] = make_float4(a10*s4, a11*s4, a12*s4, a13*s4);
}

// ------------------------------- launcher --------------------------------------
extern "C" void kernel_launch(void* const* d_in, const int* in_sizes, int n_in,
                              void* d_out, int out_size, void* d_ws, size_t ws_size,
                              hipStream_t stream) {
  const float* nf  = (const float*)d_in[0];
  const float* w1  = (const float*)d_in[1];
  const float* w2  = (const float*)d_in[2];
  const float* w3  = (const float*)d_in[3];
  const float* lw0 = (const float*)d_in[4];
  const float* lw1 = (const float*)d_in[5];
  const int*   spc = (const int*)  d_in[6];
  float* out = (float*)d_out;
  float4* wpack = (float4*)d_ws;   // E*C*64 floats = 320 KB, rebuilt every launch
  (void)ws_size; (void)in_sizes; (void)n_in; (void)out_size;

  hipLaunchKernelGGL(wt_pack, dim3((NE * NC * 16 + 255) / 256), dim3(256), 0, stream,
                     w1, w2, w3, wpack);
  hipLaunchKernelGGL(epb_main, dim3(NN / TN), dim3(256), 0, stream,
                     nf, wpack, lw0, lw1, spc, out);
}

// Round 6
// 108.620 us; speedup vs baseline: 1.4871x; 1.3203x over previous
//
#include <hip/hip_runtime.h>
#include <utility>

// EquivariantProductBasisBlock (MACE-style) for gfx950 — round 6.
// R4 lesson: VGPR cap 64 -> spill storm. R5 lesson: 64-float register array ->
// scratch demotion -> spill storm (WRITE 95MB). R6: back to R3's no-spill load
// pattern (direct per-path coalesced weight loads), attack occupancy only:
// TN=2, 256-thr blocks, 2048 blocks, 1 pair/thread. LDS 13.3KB, VGPR ~90 ->
// ~5 blocks/CU resident = 20 waves/CU vs R3's 8.

#define NN 4096
#define NC 128
#define TN 2

// ---------------------------- static_for ---------------------------------------
template<typename F, int... Is>
__device__ __forceinline__ void sfor_impl(F&& f, std::integer_sequence<int, Is...>) {
  (f(std::integral_constant<int, Is>{}), ...);
}
template<int N, typename F>
__device__ __forceinline__ void sfor(F&& f) {
  sfor_impl((F&&)f, std::make_integer_sequence<int, N>{});
}

// ---------------------------- CG metadata (constexpr) --------------------------
constexpr int T_L1c[19]  = {0,0,0,1,1,1,1,1,1,1,2,2,2,2,2,2,2,2,3};
constexpr int T_L2c[19]  = {0,1,2,0,1,1,1,2,2,2,0,1,1,1,2,2,2,2,2};
constexpr int T_L3c[19]  = {0,1,2,1,0,1,2,1,2,3,2,1,2,3,0,1,2,3,1};
constexpr int T_OFFc[19] = {0,1,10,35,44,53,80,125,170,245,350,375,420,495,600,625,700,825,1000};
constexpr int AOFFc[3]   = {0,1,4};

constexpr int P2_L1c[9]  = {0,0,1,1,1,1,2,2,2};
constexpr int P2_L2c[9]  = {0,1,0,1,1,2,1,2,2};
constexpr int P2_LOc[9]  = {0,1,1,0,1,1,1,0,1};
constexpr int P2_TBLc[9] = {0,1,3,4,5,7,11,14,15};

constexpr int K_L1c[18]  = {0,0,0,1,1,1,1,1,1,1,2,2,2,2,2,2,2,2};
constexpr int K_L2c[18]  = {0,1,2,0,1,1,1,2,2,2,0,1,1,1,2,2,2,2};
constexpr int K_L12c[18] = {0,1,2,1,0,1,2,1,2,3,2,1,2,3,0,1,2,3};

constexpr int P3_STARTc[19] = {0,2,6,9,13,15,19,22,26,29,30,33,37,40,41,43,47,50,51};
constexpr int P3_L3c[51] = {
  0,1,  0,1,1,2,  1,2,2,  0,1,1,2,  0,1,  0,1,1,2,  1,2,2,  0,1,1,2,  1,2,2,
  2,  1,2,2,  0,1,1,2,  1,2,2,  2,  0,1,  0,1,1,2,  1,2,2,  2 };
constexpr int P3_LOc[51] = {
  0,1,  1,0,1,1,  1,0,1,  1,0,1,1,  0,1,  1,0,1,1,  1,0,1,  1,0,1,1,  1,0,1,
  1,  1,0,1,  1,0,1,1,  1,0,1,  1,  0,1,  1,0,1,1,  1,0,1,  1 };
constexpr int P3_TBLc[51] = {
  0,1,  3,4,5,7,  11,14,15,  3,4,5,7,  0,1,  3,4,5,7,  11,14,15,  3,4,5,7,
  11,14,15,  18,  11,14,15,  3,4,5,7,  11,14,15,  18,  0,1,  3,4,5,7,
  11,14,15,  18 };

// ---------------------------- constexpr CG computation -------------------------
constexpr double cfact(int n) { double r = 1.0; for (int i = 2; i <= n; ++i) r *= i; return r; }
constexpr double csqrt(double x) {
  if (x <= 0.0) return 0.0;
  double r = x > 1.0 ? x : 1.0;
  for (int i = 0; i < 64; ++i) r = 0.5 * (r + x / r);
  return r;
}
constexpr double su2cg(int j1, int m1, int j2, int m2, int j3, int m3) {
  if (m3 != m1 + m2) return 0.0;
  int vmin = -j1 + j2 + m3; if (-j1 + m1 > vmin) vmin = -j1 + m1; if (vmin < 0) vmin = 0;
  int vmax = j2 + j3 + m1; if (j3 - j1 + j2 < vmax) vmax = j3 - j1 + j2; if (j3 + m3 < vmax) vmax = j3 + m3;
  double C = csqrt((2.0 * j3 + 1.0)
                   * cfact(j3 + j1 - j2) * cfact(j3 - j1 + j2) * cfact(j1 + j2 - j3)
                   * cfact(j3 + m3) * cfact(j3 - m3)
                   / (cfact(j1 + j2 + j3 + 1) * cfact(j1 - m1) * cfact(j1 + m1)
                      * cfact(j2 - m2) * cfact(j2 + m2)));
  double S = 0.0;
  for (int v = vmin; v <= vmax; ++v) {
    double sgn = ((v + j2 + m2) & 1) ? -1.0 : 1.0;
    S += sgn * cfact(j2 + j3 + m1 - v) * cfact(j1 - m1 + v)
         / (cfact(v) * cfact(j3 - j1 + j2 - v) * cfact(j3 + m3 - v) * cfact(v + j1 - j2 - m3));
  }
  return C * S;
}

struct Cx { double re, im; };
constexpr Cx cxmul(Cx a, Cx b) { return Cx{a.re * b.re - a.im * b.im, a.re * b.im + a.im * b.re}; }
struct Row { int cnt; int col[2]; Cx v[2]; };

constexpr Row c2r_row(int l, int r) {
  Row out{0, {0, 0}, {{0, 0}, {0, 0}}};
  constexpr double is2 = 0.70710678118654752440;
  const int m = r - l;
  if (m < 0) {
    out.cnt = 2;
    out.col[0] = l - m; out.v[0] = Cx{is2, 0.0};
    out.col[1] = l + m; out.v[1] = Cx{0.0, -is2};
  } else if (m == 0) {
    out.cnt = 1; out.col[0] = l; out.v[0] = Cx{1.0, 0.0};
  } else {
    const double sgn = (m & 1) ? -1.0 : 1.0;
    out.cnt = 2;
    out.col[0] = l + m; out.v[0] = Cx{sgn * is2, 0.0};
    out.col[1] = l - m; out.v[1] = Cx{0.0, sgn * is2};
  }
  const int ph = l & 3;
  for (int a = 0; a < out.cnt; ++a) {
    Cx v = out.v[a];
    out.v[a] = (ph == 0) ? v
             : (ph == 1) ? Cx{v.im, -v.re}
             : (ph == 2) ? Cx{-v.re, -v.im}
                         : Cx{-v.im, v.re};
  }
  return out;
}

struct CGAll { float v[1105]; };
constexpr CGAll make_cg() {
  CGAll R{};
  for (int t = 0; t < 19; ++t) {
    const int l1 = T_L1c[t], l2 = T_L2c[t], l3 = T_L3c[t], off = T_OFFc[t];
    const int d1 = 2 * l1 + 1, d2 = 2 * l2 + 1, d3 = 2 * l3 + 1;
    double tmp[175] = {};
    for (int i = 0; i < d1; ++i) {
      const int m1 = i - l1;
      const Row r1 = c2r_row(l1, i);
      for (int k = 0; k < d2; ++k) {
        const int m2 = k - l2, m3 = m1 + m2;
        if (m3 < -l3 || m3 > l3) continue;
        const double cc = su2cg(l1, m1, l2, m2, l3, m3);
        if (cc == 0.0) continue;
        const Row r2 = c2r_row(l2, k);
        const Row r3 = c2r_row(l3, m3 + l3);
        for (int a = 0; a < r1.cnt; ++a)
          for (int b = 0; b < r2.cnt; ++b) {
            const Cx q12 = cxmul(r1.v[a], r2.v[b]);
            for (int cdx = 0; cdx < r3.cnt; ++cdx) {
              const double re = q12.re * r3.v[cdx].re + q12.im * r3.v[cdx].im;
              tmp[(r1.col[a] * d2 + r2.col[b]) * d3 + r3.col[cdx]] += re * cc;
            }
          }
      }
    }
    const int sz = d1 * d2 * d3;
    for (int e = 0; e < sz; ++e) R.v[off + e] = (float)tmp[e];
  }
  return R;
}
constexpr CGAll CG_ALL = make_cg();

// ------------------- basis for one (node,channel) pair -------------------------
__device__ __forceinline__ void basis_pair(
    const float* __restrict__ Ap,      // 9 floats (LDS)
    const float* __restrict__ w1p,     // stride NC between paths
    const float* __restrict__ w2p,
    const float* __restrict__ w3p,
    float B[4])
{
  float A[9];
  #pragma unroll
  for (int i = 0; i < 9; ++i) A[i] = Ap[i];

  B[0] = B[1] = B[2] = B[3] = 0.f;

  // ---- order 1
  {
    const float w10 = w1p[0];
    const float w11 = w1p[NC];
    B[0] = fmaf(w10, A[0], B[0]);
    B[1] = fmaf(w11, A[1], B[1]);
    B[2] = fmaf(w11, A[2], B[2]);
    B[3] = fmaf(w11, A[3], B[3]);
  }

  // ---- order 2
  sfor<9>([&](auto P) {
    constexpr int p  = P.value;
    constexpr int l1 = P2_L1c[p], l2 = P2_L2c[p], lo = P2_LOc[p];
    constexpr int d1 = 2 * l1 + 1, d2 = 2 * l2 + 1, dl = 2 * lo + 1;
    constexpr int off = T_OFFc[P2_TBLc[p]];
    const float w = w2p[p * NC];
    sfor<dl>([&](auto Kk) {
      constexpr int k = Kk.value;
      float v = 0.f;
      sfor<d1>([&](auto I) {
        sfor<d2>([&](auto J) {
          constexpr float cgc = CG_ALL.v[off + (I.value * d2 + J.value) * dl + k];
          if constexpr (cgc != 0.0f) {
            constexpr int ia = AOFFc[l1] + I.value, ja = AOFFc[l2] + J.value;
            constexpr int x = ia < ja ? ia : ja, y = ia < ja ? ja : ia;
            v = fmaf(cgc, A[x] * A[y], v);
          }
        });
      });
      B[lo + k] = fmaf(w, v, B[lo + k]);
    });
  });

  // ---- order 3
  sfor<18>([&](auto T) {
    constexpr int t   = T.value;
    constexpr int l1  = K_L1c[t], l2 = K_L2c[t], l12 = K_L12c[t];
    constexpr int d1  = 2 * l1 + 1, d2 = 2 * l2 + 1, d12 = 2 * l12 + 1;
    constexpr int off = T_OFFc[t];
    float tt[d12];
    sfor<d12>([&](auto Kk) {
      constexpr int k = Kk.value;
      float v = 0.f;
      sfor<d1>([&](auto I) {
        sfor<d2>([&](auto J) {
          constexpr float cgc = CG_ALL.v[off + (I.value * d2 + J.value) * d12 + k];
          if constexpr (cgc != 0.0f) {
            constexpr int ia = AOFFc[l1] + I.value, ja = AOFFc[l2] + J.value;
            constexpr int x = ia < ja ? ia : ja, y = ia < ja ? ja : ia;
            v = fmaf(cgc, A[x] * A[y], v);
          }
        });
      });
      tt[k] = v;
    });
    constexpr int pcnt = P3_STARTc[t + 1] - P3_STARTc[t];
    sfor<pcnt>([&](auto PP) {
      constexpr int p  = P3_STARTc[t] + PP.value;
      constexpr int l3 = P3_L3c[p], lo = P3_LOc[p];
      constexpr int d3 = 2 * l3 + 1, dl = 2 * lo + 1;
      constexpr int off2 = T_OFFc[P3_TBLc[p]];
      const float w = w3p[p * NC];
      sfor<dl>([&](auto M) {
        float v = 0.f;
        sfor<d12>([&](auto Kk) {
          sfor<d3>([&](auto J) {
            constexpr float cgc = CG_ALL.v[off2 + (Kk.value * d3 + J.value) * dl + M.value];
            if constexpr (cgc != 0.0f)
              v = fmaf(cgc, tt[Kk.value] * A[AOFFc[l3] + J.value], v);
          });
        });
        B[lo + M.value] = fmaf(w, v, B[lo + M.value]);
      });
    });
  });
}

// ------------------------------- main kernel -----------------------------------
__global__ __launch_bounds__(256) void epb_main(
    const float* __restrict__ nf,      // [N, C, 9]
    const float* __restrict__ w1,      // [E, 2, C]
    const float* __restrict__ w2,      // [E, 9, C]
    const float* __restrict__ w3,      // [E, 51, C]
    const float* __restrict__ lw0,     // [C, F=128]
    const float* __restrict__ lw1,     // [C, F=128]
    const int*   __restrict__ species, // [N]
    float* __restrict__ out)           // [N, F, 4]
{
  __shared__ float  Anf[TN * NC * 9];  // 9.2 KB
  __shared__ float4 Bsh[TN * NC];      // 4 KB  [node][channel]
  const int t  = threadIdx.x;
  const int nb = blockIdx.x * TN;

  // ---- stage node_feats tile (coalesced float4): 576 float4 over 256 threads
  {
    const float4* src = reinterpret_cast<const float4*>(nf + (size_t)nb * (NC * 9));
    float4* dst = reinterpret_cast<float4*>(Anf);
    dst[t]       = src[t];
    dst[t + 256] = src[t + 256];
    if (t < 64) dst[t + 512] = src[t + 512];
  }
  __syncthreads();

  // ---- basis: exactly 1 (node,channel) pair per thread
  {
    const int c = t & 127, nl = t >> 7;          // nl in 0..1, wave-uniform
    const int s = species[nb + nl];
    const float* w1p = w1 + (size_t)s * 2  * NC + c;
    const float* w2p = w2 + (size_t)s * 9  * NC + c;
    const float* w3p = w3 + (size_t)s * 51 * NC + c;
    float B[4];
    basis_pair(Anf + nl * (NC * 9) + c * 9, w1p, w2p, w3p, B);
    Bsh[nl * NC + c] = make_float4(B[0], B[1], B[2], B[3]);
  }
  __syncthreads();

  // ---- linear: 1 feature x 1 node per thread (g-paired waves share lw via L1)
  const int fl = t & 127, g = t >> 7;   // g in 0..1
  const float* pa = lw0 + fl;
  const float* pb = lw1 + fl;
  const float4* bp = &Bsh[g * NC];

  float a0 = 0.f, a1 = 0.f, a2 = 0.f, a3 = 0.f;

  #pragma unroll 8
  for (int ch = 0; ch < NC; ++ch) {
    const float wa = pa[ch * NC];      // coalesced across fl
    const float wb = pb[ch * NC];
    const float4 b = bp[ch];           // wave-uniform -> LDS broadcast
    a0 = fmaf(b.x, wa, a0);
    a1 = fmaf(b.y, wb, a1);
    a2 = fmaf(b.z, wb, a2);
    a3 = fmaf(b.w, wb, a3);
  }

  const float s4 = 0.08838834764831845f;  // 1/sqrt(128)
  float4* out4 = reinterpret_cast<float4*>(out);
  out4[(size_t)(nb + g) * NC + fl] = make_float4(a0*s4, a1*s4, a2*s4, a3*s4);
}

// ------------------------------- launcher --------------------------------------
extern "C" void kernel_launch(void* const* d_in, const int* in_sizes, int n_in,
                              void* d_out, int out_size, void* d_ws, size_t ws_size,
                              hipStream_t stream) {
  const float* nf  = (const float*)d_in[0];
  const float* w1  = (const float*)d_in[1];
  const float* w2  = (const float*)d_in[2];
  const float* w3  = (const float*)d_in[3];
  const float* lw0 = (const float*)d_in[4];
  const float* lw1 = (const float*)d_in[5];
  const int*   spc = (const int*)  d_in[6];
  float* out = (float*)d_out;
  (void)d_ws; (void)ws_size; (void)in_sizes; (void)n_in; (void)out_size;

  hipLaunchKernelGGL(epb_main, dim3(NN / TN), dim3(256), 0, stream,
                     nf, w1, w2, w3, lw0, lw1, spc, out);
}

// Round 7
// 107.292 us; speedup vs baseline: 1.5056x; 1.0124x over previous
//
#include <hip/hip_runtime.h>
#include <utility>

// EquivariantProductBasisBlock (MACE-style) for gfx950 — round 7.
// Plateau diagnosis (R2/R3/R6 all ~44-48us, VALUBusy ~37%, VGPR ~124 -> 4
// waves/SIMD): 62 weight loads scattered through the unrolled basis produce
// ~13 aligned vmcnt stalls per wave. R5's preload idea was right but
// reinterpret_cast<float4*> blocked SROA -> scratch. R7: preload EVERYTHING
// (62 weights + 9 A) as scalar loads into constexpr-indexed arrays (SROA ->
// VGPRs), A read directly from global (drops Anf LDS + first barrier), ONE
// vmcnt drain, then ~850 straight-line FMAs. Linear stage = R6 form.

#define NN 4096
#define NC 128
#define TN 2

// ---------------------------- static_for ---------------------------------------
template<typename F, int... Is>
__device__ __forceinline__ void sfor_impl(F&& f, std::integer_sequence<int, Is...>) {
  (f(std::integral_constant<int, Is>{}), ...);
}
template<int N, typename F>
__device__ __forceinline__ void sfor(F&& f) {
  sfor_impl((F&&)f, std::make_integer_sequence<int, N>{});
}

// ---------------------------- CG metadata (constexpr) --------------------------
constexpr int T_L1c[19]  = {0,0,0,1,1,1,1,1,1,1,2,2,2,2,2,2,2,2,3};
constexpr int T_L2c[19]  = {0,1,2,0,1,1,1,2,2,2,0,1,1,1,2,2,2,2,2};
constexpr int T_L3c[19]  = {0,1,2,1,0,1,2,1,2,3,2,1,2,3,0,1,2,3,1};
constexpr int T_OFFc[19] = {0,1,10,35,44,53,80,125,170,245,350,375,420,495,600,625,700,825,1000};
constexpr int AOFFc[3]   = {0,1,4};

constexpr int P2_L1c[9]  = {0,0,1,1,1,1,2,2,2};
constexpr int P2_L2c[9]  = {0,1,0,1,1,2,1,2,2};
constexpr int P2_LOc[9]  = {0,1,1,0,1,1,1,0,1};
constexpr int P2_TBLc[9] = {0,1,3,4,5,7,11,14,15};

constexpr int K_L1c[18]  = {0,0,0,1,1,1,1,1,1,1,2,2,2,2,2,2,2,2};
constexpr int K_L2c[18]  = {0,1,2,0,1,1,1,2,2,2,0,1,1,1,2,2,2,2};
constexpr int K_L12c[18] = {0,1,2,1,0,1,2,1,2,3,2,1,2,3,0,1,2,3};

constexpr int P3_STARTc[19] = {0,2,6,9,13,15,19,22,26,29,30,33,37,40,41,43,47,50,51};
constexpr int P3_L3c[51] = {
  0,1,  0,1,1,2,  1,2,2,  0,1,1,2,  0,1,  0,1,1,2,  1,2,2,  0,1,1,2,  1,2,2,
  2,  1,2,2,  0,1,1,2,  1,2,2,  2,  0,1,  0,1,1,2,  1,2,2,  2 };
constexpr int P3_LOc[51] = {
  0,1,  1,0,1,1,  1,0,1,  1,0,1,1,  0,1,  1,0,1,1,  1,0,1,  1,0,1,1,  1,0,1,
  1,  1,0,1,  1,0,1,1,  1,0,1,  1,  0,1,  1,0,1,1,  1,0,1,  1 };
constexpr int P3_TBLc[51] = {
  0,1,  3,4,5,7,  11,14,15,  3,4,5,7,  0,1,  3,4,5,7,  11,14,15,  3,4,5,7,
  11,14,15,  18,  11,14,15,  3,4,5,7,  11,14,15,  18,  0,1,  3,4,5,7,
  11,14,15,  18 };

// ---------------------------- constexpr CG computation -------------------------
constexpr double cfact(int n) { double r = 1.0; for (int i = 2; i <= n; ++i) r *= i; return r; }
constexpr double csqrt(double x) {
  if (x <= 0.0) return 0.0;
  double r = x > 1.0 ? x : 1.0;
  for (int i = 0; i < 64; ++i) r = 0.5 * (r + x / r);
  return r;
}
constexpr double su2cg(int j1, int m1, int j2, int m2, int j3, int m3) {
  if (m3 != m1 + m2) return 0.0;
  int vmin = -j1 + j2 + m3; if (-j1 + m1 > vmin) vmin = -j1 + m1; if (vmin < 0) vmin = 0;
  int vmax = j2 + j3 + m1; if (j3 - j1 + j2 < vmax) vmax = j3 - j1 + j2; if (j3 + m3 < vmax) vmax = j3 + m3;
  double C = csqrt((2.0 * j3 + 1.0)
                   * cfact(j3 + j1 - j2) * cfact(j3 - j1 + j2) * cfact(j1 + j2 - j3)
                   * cfact(j3 + m3) * cfact(j3 - m3)
                   / (cfact(j1 + j2 + j3 + 1) * cfact(j1 - m1) * cfact(j1 + m1)
                      * cfact(j2 - m2) * cfact(j2 + m2)));
  double S = 0.0;
  for (int v = vmin; v <= vmax; ++v) {
    double sgn = ((v + j2 + m2) & 1) ? -1.0 : 1.0;
    S += sgn * cfact(j2 + j3 + m1 - v) * cfact(j1 - m1 + v)
         / (cfact(v) * cfact(j3 - j1 + j2 - v) * cfact(j3 + m3 - v) * cfact(v + j1 - j2 - m3));
  }
  return C * S;
}

struct Cx { double re, im; };
constexpr Cx cxmul(Cx a, Cx b) { return Cx{a.re * b.re - a.im * b.im, a.re * b.im + a.im * b.re}; }
struct Row { int cnt; int col[2]; Cx v[2]; };

constexpr Row c2r_row(int l, int r) {
  Row out{0, {0, 0}, {{0, 0}, {0, 0}}};
  constexpr double is2 = 0.70710678118654752440;
  const int m = r - l;
  if (m < 0) {
    out.cnt = 2;
    out.col[0] = l - m; out.v[0] = Cx{is2, 0.0};
    out.col[1] = l + m; out.v[1] = Cx{0.0, -is2};
  } else if (m == 0) {
    out.cnt = 1; out.col[0] = l; out.v[0] = Cx{1.0, 0.0};
  } else {
    const double sgn = (m & 1) ? -1.0 : 1.0;
    out.cnt = 2;
    out.col[0] = l + m; out.v[0] = Cx{sgn * is2, 0.0};
    out.col[1] = l - m; out.v[1] = Cx{0.0, sgn * is2};
  }
  const int ph = l & 3;
  for (int a = 0; a < out.cnt; ++a) {
    Cx v = out.v[a];
    out.v[a] = (ph == 0) ? v
             : (ph == 1) ? Cx{v.im, -v.re}
             : (ph == 2) ? Cx{-v.re, -v.im}
                         : Cx{-v.im, v.re};
  }
  return out;
}

struct CGAll { float v[1105]; };
constexpr CGAll make_cg() {
  CGAll R{};
  for (int t = 0; t < 19; ++t) {
    const int l1 = T_L1c[t], l2 = T_L2c[t], l3 = T_L3c[t], off = T_OFFc[t];
    const int d1 = 2 * l1 + 1, d2 = 2 * l2 + 1, d3 = 2 * l3 + 1;
    double tmp[175] = {};
    for (int i = 0; i < d1; ++i) {
      const int m1 = i - l1;
      const Row r1 = c2r_row(l1, i);
      for (int k = 0; k < d2; ++k) {
        const int m2 = k - l2, m3 = m1 + m2;
        if (m3 < -l3 || m3 > l3) continue;
        const double cc = su2cg(l1, m1, l2, m2, l3, m3);
        if (cc == 0.0) continue;
        const Row r2 = c2r_row(l2, k);
        const Row r3 = c2r_row(l3, m3 + l3);
        for (int a = 0; a < r1.cnt; ++a)
          for (int b = 0; b < r2.cnt; ++b) {
            const Cx q12 = cxmul(r1.v[a], r2.v[b]);
            for (int cdx = 0; cdx < r3.cnt; ++cdx) {
              const double re = q12.re * r3.v[cdx].re + q12.im * r3.v[cdx].im;
              tmp[(r1.col[a] * d2 + r2.col[b]) * d3 + r3.col[cdx]] += re * cc;
            }
          }
      }
    }
    const int sz = d1 * d2 * d3;
    for (int e = 0; e < sz; ++e) R.v[off + e] = (float)tmp[e];
  }
  return R;
}
constexpr CGAll CG_ALL = make_cg();

// ------------------------------- main kernel -----------------------------------
__global__ __launch_bounds__(256) void epb_main(
    const float* __restrict__ nf,      // [N, C, 9]
    const float* __restrict__ w1,      // [E, 2, C]
    const float* __restrict__ w2,      // [E, 9, C]
    const float* __restrict__ w3,      // [E, 51, C]
    const float* __restrict__ lw0,     // [C, F=128]
    const float* __restrict__ lw1,     // [C, F=128]
    const int*   __restrict__ species, // [N]
    float* __restrict__ out)           // [N, F, 4]
{
  __shared__ float4 Bsh[TN * NC];      // 4 KB  [node][channel]
  const int t  = threadIdx.x;
  const int nb = blockIdx.x * TN;
  const int c = t & 127, nl = t >> 7;  // nl in 0..1, wave-uniform
  const int s = species[nb + nl];      // wave-uniform (scalar load)

  // ---- issue ALL loads up-front as independent scalar loads into
  //      constexpr-indexed arrays (SROA -> VGPRs, no scratch).
  const float* w1p = w1 + (size_t)s * 2  * NC + c;
  const float* w2p = w2 + (size_t)s * 9  * NC + c;
  const float* w3p = w3 + (size_t)s * 51 * NC + c;
  const float* ap  = nf + ((size_t)(nb + nl) * NC + c) * 9;

  float w3r[51];
  sfor<51>([&](auto P) { w3r[P.value] = w3p[P.value * NC]; });
  float w2r[9];
  sfor<9>([&](auto P) { w2r[P.value] = w2p[P.value * NC]; });
  float w1r0 = w1p[0], w1r1 = w1p[NC];
  float A[9];
  sfor<9>([&](auto I) { A[I.value] = ap[I.value]; });

  // ---- basis: straight-line FMA, coefficients are instruction immediates
  float B[4];
  B[0] = w1r0 * A[0];
  B[1] = w1r1 * A[1];
  B[2] = w1r1 * A[2];
  B[3] = w1r1 * A[3];

  // order 2
  sfor<9>([&](auto P) {
    constexpr int p  = P.value;
    constexpr int l1 = P2_L1c[p], l2 = P2_L2c[p], lo = P2_LOc[p];
    constexpr int d1 = 2 * l1 + 1, d2 = 2 * l2 + 1, dl = 2 * lo + 1;
    constexpr int off = T_OFFc[P2_TBLc[p]];
    const float w = w2r[p];
    sfor<dl>([&](auto Kk) {
      constexpr int k = Kk.value;
      float v = 0.f;
      sfor<d1>([&](auto I) {
        sfor<d2>([&](auto J) {
          constexpr float cgc = CG_ALL.v[off + (I.value * d2 + J.value) * dl + k];
          if constexpr (cgc != 0.0f) {
            constexpr int ia = AOFFc[l1] + I.value, ja = AOFFc[l2] + J.value;
            constexpr int x = ia < ja ? ia : ja, y = ia < ja ? ja : ia;
            v = fmaf(cgc, A[x] * A[y], v);
          }
        });
      });
      B[lo + k] = fmaf(w, v, B[lo + k]);
    });
  });

  // order 3
  sfor<18>([&](auto T) {
    constexpr int t2  = T.value;
    constexpr int l1  = K_L1c[t2], l2 = K_L2c[t2], l12 = K_L12c[t2];
    constexpr int d1  = 2 * l1 + 1, d2 = 2 * l2 + 1, d12 = 2 * l12 + 1;
    constexpr int off = T_OFFc[t2];
    float tt[d12];
    sfor<d12>([&](auto Kk) {
      constexpr int k = Kk.value;
      float v = 0.f;
      sfor<d1>([&](auto I) {
        sfor<d2>([&](auto J) {
          constexpr float cgc = CG_ALL.v[off + (I.value * d2 + J.value) * d12 + k];
          if constexpr (cgc != 0.0f) {
            constexpr int ia = AOFFc[l1] + I.value, ja = AOFFc[l2] + J.value;
            constexpr int x = ia < ja ? ia : ja, y = ia < ja ? ja : ia;
            v = fmaf(cgc, A[x] * A[y], v);
          }
        });
      });
      tt[k] = v;
    });
    constexpr int pcnt = P3_STARTc[t2 + 1] - P3_STARTc[t2];
    sfor<pcnt>([&](auto PP) {
      constexpr int p  = P3_STARTc[t2] + PP.value;
      constexpr int l3 = P3_L3c[p], lo = P3_LOc[p];
      constexpr int d3 = 2 * l3 + 1, dl = 2 * lo + 1;
      constexpr int off2 = T_OFFc[P3_TBLc[p]];
      const float w = w3r[p];
      sfor<dl>([&](auto M) {
        float v = 0.f;
        sfor<d12>([&](auto Kk) {
          sfor<d3>([&](auto J) {
            constexpr float cgc = CG_ALL.v[off2 + (Kk.value * d3 + J.value) * dl + M.value];
            if constexpr (cgc != 0.0f)
              v = fmaf(cgc, tt[Kk.value] * A[AOFFc[l3] + J.value], v);
          });
        });
        B[lo + M.value] = fmaf(w, v, B[lo + M.value]);
      });
    });
  });

  Bsh[nl * NC + c] = make_float4(B[0], B[1], B[2], B[3]);
  __syncthreads();

  // ---- linear: 1 feature x 1 node per thread
  const int fl = t & 127, g = t >> 7;   // g in 0..1
  const float* pa = lw0 + fl;
  const float* pb = lw1 + fl;
  const float4* bp = &Bsh[g * NC];

  float a0 = 0.f, a1 = 0.f, a2 = 0.f, a3 = 0.f;

  #pragma unroll 8
  for (int ch = 0; ch < NC; ++ch) {
    const float wa = pa[ch * NC];      // coalesced across fl
    const float wb = pb[ch * NC];
    const float4 b = bp[ch];           // wave-uniform -> LDS broadcast
    a0 = fmaf(b.x, wa, a0);
    a1 = fmaf(b.y, wb, a1);
    a2 = fmaf(b.z, wb, a2);
    a3 = fmaf(b.w, wb, a3);
  }

  const float s4 = 0.08838834764831845f;  // 1/sqrt(128)
  float4* out4 = reinterpret_cast<float4*>(out);
  out4[(size_t)(nb + g) * NC + fl] = make_float4(a0*s4, a1*s4, a2*s4, a3*s4);
}

// ------------------------------- launcher --------------------------------------
extern "C" void kernel_launch(void* const* d_in, const int* in_sizes, int n_in,
                              void* d_out, int out_size, void* d_ws, size_t ws_size,
                              hipStream_t stream) {
  const float* nf  = (const float*)d_in[0];
  const float* w1  = (const float*)d_in[1];
  const float* w2  = (const float*)d_in[2];
  const float* w3  = (const float*)d_in[3];
  const float* lw0 = (const float*)d_in[4];
  const float* lw1 = (const float*)d_in[5];
  const int*   spc = (const int*)  d_in[6];
  float* out = (float*)d_out;
  (void)d_ws; (void)ws_size; (void)in_sizes; (void)n_in; (void)out_size;

  hipLaunchKernelGGL(epb_main, dim3(NN / TN), dim3(256), 0, stream,
                     nf, w1, w2, w3, lw0, lw1, spc, out);
}

// Round 8
// 105.009 us; speedup vs baseline: 1.5383x; 1.0217x over previous
//
#include <hip/hip_runtime.h>
#include <utility>

// EquivariantProductBasisBlock (MACE-style) for gfx950 — round 8.
// R2/R3/R6/R7 all plateau at ~44us regardless of occupancy/L2 traffic ->
// common factor = ~2.7M VMEM instructions (esp. linear stage: 256 scalar
// loads/wave). R8: (1) linear stage float4 weight loads + ch-split over the
// 4 waves + LDS partial reduction (256->64 VMEM/wave); (2) basis weights from
// packed [E][quad][C] records, 16 coalesced dwordx4 (62->16); (3) CG exchange
// symmetry (static_assert-verified) removes 5 dup T12 keys + merges 2 order-2
// paths. No VGPR caps (R4 lesson), no reinterpret_cast arrays (R5 lesson).

#define NN 4096
#define NC 128
#define NE 10
#define TN 2

// ---------------------------- static_for ---------------------------------------
template<typename F, int... Is>
__device__ __forceinline__ void sfor_impl(F&& f, std::integer_sequence<int, Is...>) {
  (f(std::integral_constant<int, Is>{}), ...);
}
template<int N, typename F>
__device__ __forceinline__ void sfor(F&& f) {
  sfor_impl((F&&)f, std::make_integer_sequence<int, N>{});
}

// ---------------------------- CG metadata (constexpr) --------------------------
constexpr int T_L1c[19]  = {0,0,0,1,1,1,1,1,1,1,2,2,2,2,2,2,2,2,3};
constexpr int T_L2c[19]  = {0,1,2,0,1,1,1,2,2,2,0,1,1,1,2,2,2,2,2};
constexpr int T_L3c[19]  = {0,1,2,1,0,1,2,1,2,3,2,1,2,3,0,1,2,3,1};
constexpr int T_OFFc[19] = {0,1,10,35,44,53,80,125,170,245,350,375,420,495,600,625,700,825,1000};
constexpr int AOFFc[3]   = {0,1,4};

// order-2: unique paths after merging (1,0,1)->(0,1,1) and (2,1,1)->(1,2,1)
// (both exchange signs are +1; verified by static_assert below)
constexpr int P2U_L1c[7]  = {0,0,1,1,1,2,2};
constexpr int P2U_L2c[7]  = {0,1,1,1,2,2,2};
constexpr int P2U_LOc[7]  = {0,1,0,1,1,0,1};
constexpr int P2U_TBLc[7] = {0,1,4,5,7,14,15};
constexpr int P2U_WAc[7]  = {0,1,3,4,5,7,8};    // w2 path index
constexpr int P2U_WBc[7]  = {-1,2,-1,-1,6,-1,-1}; // merged second w2 index

constexpr int K_L1c[18]  = {0,0,0,1,1,1,1,1,1,1,2,2,2,2,2,2,2,2};
constexpr int K_L2c[18]  = {0,1,2,0,1,1,1,2,2,2,0,1,1,1,2,2,2,2};
constexpr int K_L12c[18] = {0,1,2,1,0,1,2,1,2,3,2,1,2,3,0,1,2,3};

// T12 exchange-symmetry mapping: key t duplicates TT_CANON[t] with sign TT_SGN[t]
constexpr int   TT_CANONc[18] = {0,1,2,1,4,5,6,7,8,9,2,7,8,9,14,15,16,17};
constexpr float TT_SGNc[18]   = {1,1,1,1,1,1,1,1,1,1,1,1,-1,1,1,1,1,1};
constexpr int CANONc[13] = {0,1,2,4,5,6,7,8,9,14,15,16,17};
constexpr int CONS2c[13] = {-1,3,10,-1,-1,-1,11,12,13,-1,-1,-1,-1};

constexpr int P3_STARTc[19] = {0,2,6,9,13,15,19,22,26,29,30,33,37,40,41,43,47,50,51};
constexpr int P3_L3c[51] = {
  0,1,  0,1,1,2,  1,2,2,  0,1,1,2,  0,1,  0,1,1,2,  1,2,2,  0,1,1,2,  1,2,2,
  2,  1,2,2,  0,1,1,2,  1,2,2,  2,  0,1,  0,1,1,2,  1,2,2,  2 };
constexpr int P3_LOc[51] = {
  0,1,  1,0,1,1,  1,0,1,  1,0,1,1,  0,1,  1,0,1,1,  1,0,1,  1,0,1,1,  1,0,1,
  1,  1,0,1,  1,0,1,1,  1,0,1,  1,  0,1,  1,0,1,1,  1,0,1,  1 };
constexpr int P3_TBLc[51] = {
  0,1,  3,4,5,7,  11,14,15,  3,4,5,7,  0,1,  3,4,5,7,  11,14,15,  3,4,5,7,
  11,14,15,  18,  11,14,15,  3,4,5,7,  11,14,15,  18,  0,1,  3,4,5,7,
  11,14,15,  18 };

// ---------------------------- constexpr CG computation -------------------------
constexpr double cfact(int n) { double r = 1.0; for (int i = 2; i <= n; ++i) r *= i; return r; }
constexpr double csqrt(double x) {
  if (x <= 0.0) return 0.0;
  double r = x > 1.0 ? x : 1.0;
  for (int i = 0; i < 64; ++i) r = 0.5 * (r + x / r);
  return r;
}
constexpr double su2cg(int j1, int m1, int j2, int m2, int j3, int m3) {
  if (m3 != m1 + m2) return 0.0;
  int vmin = -j1 + j2 + m3; if (-j1 + m1 > vmin) vmin = -j1 + m1; if (vmin < 0) vmin = 0;
  int vmax = j2 + j3 + m1; if (j3 - j1 + j2 < vmax) vmax = j3 - j1 + j2; if (j3 + m3 < vmax) vmax = j3 + m3;
  double C = csqrt((2.0 * j3 + 1.0)
                   * cfact(j3 + j1 - j2) * cfact(j3 - j1 + j2) * cfact(j1 + j2 - j3)
                   * cfact(j3 + m3) * cfact(j3 - m3)
                   / (cfact(j1 + j2 + j3 + 1) * cfact(j1 - m1) * cfact(j1 + m1)
                      * cfact(j2 - m2) * cfact(j2 + m2)));
  double S = 0.0;
  for (int v = vmin; v <= vmax; ++v) {
    double sgn = ((v + j2 + m2) & 1) ? -1.0 : 1.0;
    S += sgn * cfact(j2 + j3 + m1 - v) * cfact(j1 - m1 + v)
         / (cfact(v) * cfact(j3 - j1 + j2 - v) * cfact(j3 + m3 - v) * cfact(v + j1 - j2 - m3));
  }
  return C * S;
}

struct Cx { double re, im; };
constexpr Cx cxmul(Cx a, Cx b) { return Cx{a.re * b.re - a.im * b.im, a.re * b.im + a.im * b.re}; }
struct Row { int cnt; int col[2]; Cx v[2]; };

constexpr Row c2r_row(int l, int r) {
  Row out{0, {0, 0}, {{0, 0}, {0, 0}}};
  constexpr double is2 = 0.70710678118654752440;
  const int m = r - l;
  if (m < 0) {
    out.cnt = 2;
    out.col[0] = l - m; out.v[0] = Cx{is2, 0.0};
    out.col[1] = l + m; out.v[1] = Cx{0.0, -is2};
  } else if (m == 0) {
    out.cnt = 1; out.col[0] = l; out.v[0] = Cx{1.0, 0.0};
  } else {
    const double sgn = (m & 1) ? -1.0 : 1.0;
    out.cnt = 2;
    out.col[0] = l + m; out.v[0] = Cx{sgn * is2, 0.0};
    out.col[1] = l - m; out.v[1] = Cx{0.0, sgn * is2};
  }
  const int ph = l & 3;
  for (int a = 0; a < out.cnt; ++a) {
    Cx v = out.v[a];
    out.v[a] = (ph == 0) ? v
             : (ph == 1) ? Cx{v.im, -v.re}
             : (ph == 2) ? Cx{-v.re, -v.im}
                         : Cx{-v.im, v.re};
  }
  return out;
}

struct CGAll { float v[1105]; };
constexpr CGAll make_cg() {
  CGAll R{};
  for (int t = 0; t < 19; ++t) {
    const int l1 = T_L1c[t], l2 = T_L2c[t], l3 = T_L3c[t], off = T_OFFc[t];
    const int d1 = 2 * l1 + 1, d2 = 2 * l2 + 1, d3 = 2 * l3 + 1;
    double tmp[175] = {};
    for (int i = 0; i < d1; ++i) {
      const int m1 = i - l1;
      const Row r1 = c2r_row(l1, i);
      for (int k = 0; k < d2; ++k) {
        const int m2 = k - l2, m3 = m1 + m2;
        if (m3 < -l3 || m3 > l3) continue;
        const double cc = su2cg(l1, m1, l2, m2, l3, m3);
        if (cc == 0.0) continue;
        const Row r2 = c2r_row(l2, k);
        const Row r3 = c2r_row(l3, m3 + l3);
        for (int a = 0; a < r1.cnt; ++a)
          for (int b = 0; b < r2.cnt; ++b) {
            const Cx q12 = cxmul(r1.v[a], r2.v[b]);
            for (int cdx = 0; cdx < r3.cnt; ++cdx) {
              const double re = q12.re * r3.v[cdx].re + q12.im * r3.v[cdx].im;
              tmp[(r1.col[a] * d2 + r2.col[b]) * d3 + r3.col[cdx]] += re * cc;
            }
          }
      }
    }
    const int sz = d1 * d2 * d3;
    for (int e = 0; e < sz; ++e) R.v[off + e] = (float)tmp[e];
  }
  return R;
}
constexpr CGAll CG_ALL = make_cg();

// compile-time proof of the exchange symmetry used for tt-sharing & path merging
constexpr bool check_cg_sym() {
  for (int t = 0; t < 18; ++t) {
    const int tc = TT_CANONc[t];
    if (tc == t) continue;
    const int l1 = K_L1c[t], l2 = K_L2c[t], l12 = K_L12c[t];
    const int d1 = 2*l1+1, d2 = 2*l2+1, d12 = 2*l12+1;
    for (int i = 0; i < d1; ++i)
      for (int j = 0; j < d2; ++j)
        for (int k = 0; k < d12; ++k) {
          float a = CG_ALL.v[T_OFFc[t]  + (i*d2 + j)*d12 + k];
          float b = TT_SGNc[t] * CG_ALL.v[T_OFFc[tc] + (j*d1 + i)*d12 + k];
          float d = a - b; if (d < 0) d = -d;
          if (d > 1e-5f) return false;
        }
  }
  return true;
}
static_assert(check_cg_sym(), "CG exchange symmetry violated");

// ------------------- weight pack: [E][quad 0..15][C] float4 --------------------
// path index p: 0..1 = w1, 2..10 = w2, 11..61 = w3, 62..63 = 0; quad i = p/4.
__global__ __launch_bounds__(256) void wt_pack(
    const float* __restrict__ w1, const float* __restrict__ w2,
    const float* __restrict__ w3, float4* __restrict__ wpack)
{
  const int tid = blockIdx.x * 256 + threadIdx.x;   // NE*16*NC = 20480
  if (tid >= NE * 16 * NC) return;
  const int e = tid / (16 * NC);
  const int r = tid % (16 * NC);
  const int i = r / NC;
  const int c = r % NC;
  float v[4];
  #pragma unroll
  for (int j = 0; j < 4; ++j) {
    const int p = i * 4 + j;
    float x = 0.f;
    if (p < 2)       x = w1[((size_t)e * 2  + p)        * NC + c];
    else if (p < 11) x = w2[((size_t)e * 9  + (p - 2))  * NC + c];
    else if (p < 62) x = w3[((size_t)e * 51 + (p - 11)) * NC + c];
    v[j] = x;
  }
  wpack[tid] = make_float4(v[0], v[1], v[2], v[3]);
}

// ------------------------------- main kernel -----------------------------------
__global__ __launch_bounds__(256) void epb_main(
    const float*  __restrict__ nf,      // [N, C, 9]
    const float4* __restrict__ wpack,   // [E][16][C]
    const float*  __restrict__ lw0,     // [C, F=128]
    const float*  __restrict__ lw1,     // [C, F=128]
    const int*    __restrict__ species, // [N]
    float* __restrict__ out)            // [N, F, 4]
{
  __shared__ float4 Bsh[TN * NC];       // 4 KB   [node][channel]
  __shared__ float4 psh[4 * TN * NC];   // 16 KB  [kp][node][feature] (m0..m3)
  const int t  = threadIdx.x;
  const int nb = blockIdx.x * TN;

  // ================= basis: 1 (node,channel) pair per thread ===================
  {
    const int c = t & 127, nl = t >> 7;
    const int s = species[nb + nl];     // wave-uniform

    // 16 coalesced dwordx4 weight loads into constexpr-indexed scalars (SROA)
    float wr[64];
    {
      const float4* wp = wpack + ((size_t)s * 16) * NC + c;
      sfor<16>([&](auto I) {
        const float4 v = wp[I.value * NC];
        wr[4*I.value+0] = v.x; wr[4*I.value+1] = v.y;
        wr[4*I.value+2] = v.z; wr[4*I.value+3] = v.w;
      });
    }
    // A direct from global (9 scalars, wave-coalesced at stride 36B)
    const float* ap = nf + ((size_t)(nb + nl) * NC + c) * 9;
    float A[9];
    sfor<9>([&](auto I) { A[I.value] = ap[I.value]; });

    float B[4];
    B[0] = wr[0] * A[0];
    B[1] = wr[1] * A[1];
    B[2] = wr[1] * A[2];
    B[3] = wr[1] * A[3];

    // ---- order 2 (unique paths, merged weights)
    sfor<7>([&](auto P) {
      constexpr int p  = P.value;
      constexpr int l1 = P2U_L1c[p], l2 = P2U_L2c[p], lo = P2U_LOc[p];
      constexpr int d1 = 2*l1+1, d2 = 2*l2+1, dl = 2*lo+1;
      constexpr int off = T_OFFc[P2U_TBLc[p]];
      float w = wr[2 + P2U_WAc[p]];
      if constexpr (P2U_WBc[p] >= 0) w += wr[2 + P2U_WBc[p]];
      sfor<dl>([&](auto Kk) {
        constexpr int k = Kk.value;
        float v = 0.f;
        sfor<d1>([&](auto I) {
          sfor<d2>([&](auto J) {
            constexpr float cgc = CG_ALL.v[off + (I.value * d2 + J.value) * dl + k];
            if constexpr (cgc != 0.0f) {
              constexpr int ia = AOFFc[l1] + I.value, ja = AOFFc[l2] + J.value;
              constexpr int x = ia < ja ? ia : ja, y = ia < ja ? ja : ia;
              v = fmaf(cgc, A[x] * A[y], v);
            }
          });
        });
        B[lo + k] = fmaf(w, v, B[lo + k]);
      });
    });

    // ---- order 3: 13 canonical T12 keys; dup keys consume the shared tt
    sfor<13>([&](auto CI) {
      constexpr int tk  = CANONc[CI.value];
      constexpr int l1  = K_L1c[tk], l2 = K_L2c[tk], l12 = K_L12c[tk];
      constexpr int d1  = 2*l1+1, d2 = 2*l2+1, d12 = 2*l12+1;
      constexpr int off = T_OFFc[tk];
      float tt[d12];
      sfor<d12>([&](auto Kk) {
        constexpr int k = Kk.value;
        float v = 0.f;
        sfor<d1>([&](auto I) {
          sfor<d2>([&](auto J) {
            constexpr float cgc = CG_ALL.v[off + (I.value * d2 + J.value) * d12 + k];
            if constexpr (cgc != 0.0f) {
              constexpr int ia = AOFFc[l1] + I.value, ja = AOFFc[l2] + J.value;
              constexpr int x = ia < ja ? ia : ja, y = ia < ja ? ja : ia;
              v = fmaf(cgc, A[x] * A[y], v);
            }
          });
        });
        tt[k] = v;
      });

      auto consume = [&](auto TK, auto SG) {
        constexpr int tkey = TK.value;
        constexpr float sgn = (float)SG.value;
        constexpr int pcnt = P3_STARTc[tkey + 1] - P3_STARTc[tkey];
        sfor<pcnt>([&](auto PP) {
          constexpr int p  = P3_STARTc[tkey] + PP.value;
          constexpr int l3 = P3_L3c[p], lo = P3_LOc[p];
          constexpr int d3 = 2*l3+1, dl = 2*lo+1;
          constexpr int off2 = T_OFFc[P3_TBLc[p]];
          const float w = wr[11 + p];
          sfor<dl>([&](auto M) {
            float v = 0.f;
            sfor<d12>([&](auto Kk) {
              sfor<d3>([&](auto J) {
                constexpr float cgc = sgn * CG_ALL.v[off2 + (Kk.value * d3 + J.value) * dl + M.value];
                if constexpr (cgc != 0.0f)
                  v = fmaf(cgc, tt[Kk.value] * A[AOFFc[l3] + J.value], v);
              });
            });
            B[lo + M.value] = fmaf(w, v, B[lo + M.value]);
          });
        });
      };
      consume(std::integral_constant<int, tk>{}, std::integral_constant<int, 1>{});
      constexpr int td = CONS2c[CI.value];
      if constexpr (td >= 0)
        consume(std::integral_constant<int, td>{},
                std::integral_constant<int, (int)TT_SGNc[td]>{});
    });

    Bsh[nl * NC + c] = make_float4(B[0], B[1], B[2], B[3]);
  }
  __syncthreads();

  // ============ linear: float4 weights, ch-split over 4 waves ==================
  {
    const int q  = t & 31;         // feature quad: features 4q..4q+3
    const int g  = (t >> 5) & 1;   // node
    const int kp = t >> 6;         // channel quarter (== wave id)
    const float4* pa4 = reinterpret_cast<const float4*>(lw0) + q;
    const float4* pb4 = reinterpret_cast<const float4*>(lw1) + q;
    const float4* bp  = &Bsh[g * NC + kp * 32];

    // of[d] = (m0,m1,m2,m3) accumulator for feature 4q+d
    float4 of0{0,0,0,0}, of1{0,0,0,0}, of2{0,0,0,0}, of3{0,0,0,0};

    #pragma unroll 4
    for (int ch2 = 0; ch2 < 32; ++ch2) {
      const int ch = kp * 32 + ch2;
      const float4 wa = pa4[ch * 32];   // dwordx4, 512B/wave-half, coalesced
      const float4 wb = pb4[ch * 32];
      const float4 b  = bp[ch2];        // 2 uniform addrs/wave -> broadcast
      of0.x = fmaf(b.x, wa.x, of0.x); of0.y = fmaf(b.y, wb.x, of0.y);
      of0.z = fmaf(b.z, wb.x, of0.z); of0.w = fmaf(b.w, wb.x, of0.w);
      of1.x = fmaf(b.x, wa.y, of1.x); of1.y = fmaf(b.y, wb.y, of1.y);
      of1.z = fmaf(b.z, wb.y, of1.z); of1.w = fmaf(b.w, wb.y, of1.w);
      of2.x = fmaf(b.x, wa.z, of2.x); of2.y = fmaf(b.y, wb.z, of2.y);
      of2.z = fmaf(b.z, wb.z, of2.z); of2.w = fmaf(b.w, wb.z, of2.w);
      of3.x = fmaf(b.x, wa.w, of3.x); of3.y = fmaf(b.y, wb.w, of3.y);
      of3.z = fmaf(b.z, wb.w, of3.z); of3.w = fmaf(b.w, wb.w, of3.w);
    }
    float4* pp = &psh[((kp * TN + g) * NC) + 4 * q];
    pp[0] = of0; pp[1] = of1; pp[2] = of2; pp[3] = of3;
  }
  __syncthreads();

  // ---- reduce partials over kp and store
  {
    const int f = t & 127, g2 = t >> 7;
    const float4 p0 = psh[((0 * TN + g2) * NC) + f];
    const float4 p1 = psh[((1 * TN + g2) * NC) + f];
    const float4 p2 = psh[((2 * TN + g2) * NC) + f];
    const float4 p3 = psh[((3 * TN + g2) * NC) + f];
    const float s4 = 0.08838834764831845f;  // 1/sqrt(128)
    float4 r;
    r.x = (p0.x + p1.x + p2.x + p3.x) * s4;
    r.y = (p0.y + p1.y + p2.y + p3.y) * s4;
    r.z = (p0.z + p1.z + p2.z + p3.z) * s4;
    r.w = (p0.w + p1.w + p2.w + p3.w) * s4;
    reinterpret_cast<float4*>(out)[(size_t)(nb + g2) * NC + f] = r;
  }
}

// ------------------------------- launcher --------------------------------------
extern "C" void kernel_launch(void* const* d_in, const int* in_sizes, int n_in,
                              void* d_out, int out_size, void* d_ws, size_t ws_size,
                              hipStream_t stream) {
  const float* nf  = (const float*)d_in[0];
  const float* w1  = (const float*)d_in[1];
  const float* w2  = (const float*)d_in[2];
  const float* w3  = (const float*)d_in[3];
  const float* lw0 = (const float*)d_in[4];
  const float* lw1 = (const float*)d_in[5];
  const int*   spc = (const int*)  d_in[6];
  float* out = (float*)d_out;
  float4* wpack = (float4*)d_ws;   // NE*16*NC float4 = 320 KB, rebuilt each launch
  (void)ws_size; (void)in_sizes; (void)n_in; (void)out_size;

  hipLaunchKernelGGL(wt_pack, dim3((NE * 16 * NC + 255) / 256), dim3(256), 0, stream,
                     w1, w2, w3, wpack);
  hipLaunchKernelGGL(epb_main, dim3(NN / TN), dim3(256), 0, stream,
                     nf, wpack, lw0, lw1, spc, out);
}